// Round 15
// baseline (108.192 us; speedup 1.0000x reference)
//
#include <hip/hip_runtime.h>
#include <float.h>

#define B_CONST 8
#define ONE_BF 0x3F80u          // bf16(1.0)

typedef short short8 __attribute__((ext_vector_type(8)));
typedef float f32x4  __attribute__((ext_vector_type(4)));

__device__ __forceinline__ unsigned short f2bf(float f) {   // RNE f32->bf16
    unsigned u = __float_as_uint(f);
    return (unsigned short)((u + 0x7FFFu + ((u >> 16) & 1u)) >> 16);
}
__device__ __forceinline__ float bf2f(unsigned short h) {
    return __uint_as_float(((unsigned)h) << 16);
}
__device__ __forceinline__ float min3(float a, float b, float c) {
    float d;
    asm("v_min3_f32 %0, %1, %2, %3" : "=v"(d) : "v"(a), "v"(b), "v"(c));
    return d;
}

// MFMA kernel, r14 K-packing (verified absmax 0.0), restructured loops:
// wave w owns 16 ref tiles; 8 query strips inner with A-frags register-resident.
// ONE mfma_f32_16x16x32_bf16 emits a complete 16x16 tile of
// d = qw + rw - 2 q.r via split-bf16 K-slots:
//   k0-2:(-2hq)(hr)  k3-5:(-2eq)(hr)  k6-8:(hq)(-2er)  k9-10:(1)(hrw,erw)
//   k11-12:(hqw,eqw)(1)
// Row-mins: rm[8][4] regs across js, shuffle-tree at end. Col-mins: 1 reg
// across strips, 2 shuffles + plain ds_write per j. NO LDS atomics (r14's
// 8192 LDS atomicMins/block were the 37us -> this removes them all).
__global__ __launch_bounds__(256) void hd_mfma(
    const float* __restrict__ p1, const float* __restrict__ p2,
    float* __restrict__ part_row, float* __restrict__ part_col,
    unsigned int* __restrict__ comm, int N, int M) {
    int t = threadIdx.x;
    int blk = blockIdx.x;
    if (blk == 0 && t < 9) comm[t] = 0u;

    int gCount  = M >> 10;               // 1024-ref col groups
    int rbCount = N >> 7;                // 128-query row blocks
    int perB = rbCount * gCount;
    int b   = blk / perB;
    int rem = blk - b * perB;
    int rb  = rem / gCount;
    int g   = rem - rb * gCount;

    __shared__ unsigned short ldsBlo[8192];   // B k0-7  per ref (16KB)
    __shared__ unsigned short ldsBhi[8192];   // B k8-15 per ref (16KB)
    __shared__ unsigned short ldsA0[1024];    // A k0-7  per query (2KB)
    __shared__ unsigned short ldsAhi[1024];   // A k8-15 per query (2KB)
    __shared__ unsigned short ldsZero[8];
    __shared__ float ldsCol[1024];            // col-min per ref (4KB)
    __shared__ float ldsRowW[512];            // per-wave row-mins (2KB)

    if (t < 8) ldsZero[t] = 0;

    // ---- prep: fragments for this block's 1024 refs / 128 queries
    const float* rsrc = p2 + 3 * ((size_t)b * M + ((size_t)g << 10));
    for (int i = t; i < 1024; i += 256) {
        float x = rsrc[3*i], y = rsrc[3*i+1], z = rsrc[3*i+2];
        unsigned short hx = f2bf(x), hy = f2bf(y), hz = f2bf(z);
        float ex = x - bf2f(hx), ey = y - bf2f(hy), ez = z - bf2f(hz);
        unsigned short m2ex = f2bf(-2.f*ex), m2ey = f2bf(-2.f*ey), m2ez = f2bf(-2.f*ez);
        float rw = fmaf(x,x,fmaf(y,y,z*z));
        unsigned short hrw = f2bf(rw);
        unsigned short erw = f2bf(rw - bf2f(hrw));
        unsigned* lo = (unsigned*)(ldsBlo + i*8);   // [hx,hy,hz,hx,hy,hz,-2ex,-2ey]
        lo[0] = hx | ((unsigned)hy << 16);
        lo[1] = hz | ((unsigned)hx << 16);
        lo[2] = hy | ((unsigned)hz << 16);
        lo[3] = m2ex | ((unsigned)m2ey << 16);
        unsigned* hi = (unsigned*)(ldsBhi + i*8);   // [-2ez,hrw,erw,1,1,0,0,0]
        hi[0] = m2ez | ((unsigned)hrw << 16);
        hi[1] = erw | (ONE_BF << 16);
        hi[2] = ONE_BF;
        hi[3] = 0;
    }
    const float* qsrc = p1 + 3 * ((size_t)b * N + ((size_t)rb << 7));
    if (t < 128) {
        float x = qsrc[3*t], y = qsrc[3*t+1], z = qsrc[3*t+2];
        unsigned short hx = f2bf(x), hy = f2bf(y), hz = f2bf(z);
        float ex = x - bf2f(hx), ey = y - bf2f(hy), ez = z - bf2f(hz);
        float qw = fmaf(x,x,fmaf(y,y,z*z));
        unsigned short hqw = f2bf(qw);
        unsigned short eqw = f2bf(qw - bf2f(hqw));
        unsigned* a0 = (unsigned*)(ldsA0 + t*8);    // [-2hx,-2hy,-2hz,-2ex,-2ey,-2ez,hx,hy]
        a0[0] = f2bf(-2.f*bf2f(hx)) | ((unsigned)f2bf(-2.f*bf2f(hy)) << 16);
        a0[1] = f2bf(-2.f*bf2f(hz)) | ((unsigned)f2bf(-2.f*ex) << 16);
        a0[2] = f2bf(-2.f*ey) | ((unsigned)f2bf(-2.f*ez) << 16);
        a0[3] = hx | ((unsigned)hy << 16);
        unsigned* ah = (unsigned*)(ldsAhi + t*8);   // [hz,1,1,hqw,eqw,0,0,0]
        ah[0] = hz | (ONE_BF << 16);
        ah[1] = ONE_BF | ((unsigned)hqw << 16);
        ah[2] = eqw;
        ah[3] = 0;
    }
    __syncthreads();

    int l = t & 63, w = t >> 6;
    int n = l & 15, quad = l >> 4;

    // A-frags for all 8 strips, register-resident (32 VGPRs).
    const unsigned short* abase = (quad == 0) ? ldsA0 : (quad == 1) ? ldsAhi : ldsZero;
    int astride = (quad < 2) ? 8 : 0;
    short8 A[8];
    #pragma unroll
    for (int s = 0; s < 8; ++s)
        A[s] = *(const short8*)(abase + ((s << 4) + n) * astride);

    const unsigned short* bbase = (quad == 0) ? ldsBlo : (quad == 1) ? ldsBhi : ldsZero;
    int bstride = (quad < 2) ? 8 : 0;

    f32x4 zacc = {0.f, 0.f, 0.f, 0.f};
    float rm[8][4];
    #pragma unroll
    for (int s = 0; s < 8; ++s)
        { rm[s][0]=FLT_MAX; rm[s][1]=FLT_MAX; rm[s][2]=FLT_MAX; rm[s][3]=FLT_MAX; }

    // Wave w covers ref tiles j in [w*16, w*16+16).
    for (int j = (w << 4); j < (w << 4) + 16; ++j) {
        short8 Bf = *(const short8*)(bbase + ((j << 4) + n) * bstride);
        float cm = FLT_MAX;
        #pragma unroll
        for (int s = 0; s < 8; ++s) {
            f32x4 D = __builtin_amdgcn_mfma_f32_16x16x32_bf16(A[s], Bf, zacc, 0, 0, 0);
            rm[s][0] = fminf(rm[s][0], D[0]);
            rm[s][1] = fminf(rm[s][1], D[1]);
            rm[s][2] = fminf(rm[s][2], D[2]);
            rm[s][3] = fminf(rm[s][3], D[3]);
            cm = fminf(cm, fminf(min3(D[0], D[1], D[2]), D[3]));
        }
        cm = fminf(cm, __shfl_xor(cm, 16, 64));      // combine 4 quads
        cm = fminf(cm, __shfl_xor(cm, 32, 64));
        if (quad == 0) ldsCol[(j << 4) + n] = cm;    // plain write, wave-private j
    }

    // Row-min: reduce across the 16 cols (lanes n within each quad).
    #pragma unroll
    for (int s = 0; s < 8; ++s) {
        #pragma unroll
        for (int msk = 1; msk < 16; msk <<= 1) {
            rm[s][0] = fminf(rm[s][0], __shfl_xor(rm[s][0], msk, 64));
            rm[s][1] = fminf(rm[s][1], __shfl_xor(rm[s][1], msk, 64));
            rm[s][2] = fminf(rm[s][2], __shfl_xor(rm[s][2], msk, 64));
            rm[s][3] = fminf(rm[s][3], __shfl_xor(rm[s][3], msk, 64));
        }
    }
    if (n == 0) {                                    // C/D row = quad*4 + reg (m89)
        #pragma unroll
        for (int s = 0; s < 8; ++s) {
            float* rr = ldsRowW + (w << 7) + (s << 4) + (quad << 2);
            rr[0] = rm[s][0]; rr[1] = rm[s][1]; rr[2] = rm[s][2]; rr[3] = rm[s][3];
        }
    }
    __syncthreads();

    if (t < 128) {
        float m = fminf(fminf(ldsRowW[t], ldsRowW[128 + t]),
                        fminf(ldsRowW[256 + t], ldsRowW[384 + t]));
        part_row[((size_t)g * B_CONST + b) * N + ((size_t)rb << 7) + t] = fmaxf(m, 0.f);
    }
    for (int i = t; i < 1024; i += 256)
        part_col[((size_t)b * rbCount + rb) * M + ((size_t)g << 10) + i] =
            fmaxf(ldsCol[i], 0.f);
}

// 128 blocks: (dir, b, query-slice). dir0: min over gCount row-partials (dist1);
// dir1: min over rbCount col-partials (dist2). max over slice -> atomicMax
// comm[b]; ticket 127 sums into out[0].
__global__ __launch_bounds__(256) void hd_final(
    const float* __restrict__ part_row, const float* __restrict__ part_col,
    unsigned int* __restrict__ comm, float* __restrict__ out, int N, int M) {
    int db  = blockIdx.x >> 3;
    int qs  = blockIdx.x & 7;
    int dir = db >> 3;
    int bb  = db & 7;
    int G   = dir ? (N >> 7) : (M >> 10);
    int QN  = dir ? M : N;
    const float* base = dir ? part_col + (size_t)bb * (N >> 7) * M
                            : part_row + (size_t)bb * N;
    size_t gstride = dir ? (size_t)M : (size_t)B_CONST * N;

    int span = QN >> 3;
    int q0 = qs * span;
    float mx = 0.f;
    for (int qq = q0 + threadIdx.x; qq < q0 + span; qq += 256) {
        float mm = base[qq];
        for (int gg = 1; gg < G; ++gg)
            mm = fminf(mm, base[(size_t)gg * gstride + qq]);
        mx = fmaxf(mx, mm);
    }
    #pragma unroll
    for (int off = 32; off > 0; off >>= 1)
        mx = fmaxf(mx, __shfl_down(mx, off, 64));
    __shared__ float wred[4];
    int l = threadIdx.x & 63, w = threadIdx.x >> 6;
    if (l == 0) wred[w] = mx;
    __syncthreads();
    if (threadIdx.x == 0) {
        mx = fmaxf(fmaxf(wred[0], wred[1]), fmaxf(wred[2], wred[3]));
        atomicMax(&comm[bb], __float_as_uint(mx));
        __threadfence();
        unsigned int t2 = atomicAdd(&comm[8], 1u);
        if (t2 == 127u) {
            float s = 0.f;
            for (int k = 0; k < B_CONST; ++k)
                s += __uint_as_float(atomicMax(&comm[k], 0u));
            out[0] = s;
        }
    }
}

extern "C" void kernel_launch(void* const* d_in, const int* in_sizes, int n_in,
                              void* d_out, int out_size, void* d_ws, size_t ws_size,
                              hipStream_t stream) {
    const float* p1 = (const float*)d_in[0];
    const float* p2 = (const float*)d_in[1];
    const int B = B_CONST;
    int N = in_sizes[0] / (3 * B);
    int M = in_sizes[1] / (3 * B);

    float* part_row = (float*)d_ws;                               // (M>>10)*B*N
    float* part_col = part_row + (size_t)(M >> 10) * B * N;       // (N>>7)*B*M
    unsigned int* comm = (unsigned int*)(part_col + (size_t)(N >> 7) * B * M);

    int blocks = B * (N >> 7) * (M >> 10);    // 1024
    hd_mfma<<<blocks, 256, 0, stream>>>(p1, p2, part_row, part_col, comm, N, M);
    hd_final<<<128, 256, 0, stream>>>(part_row, part_col, comm, (float*)d_out, N, M);
}